// Round 5
// baseline (625.558 us; speedup 1.0000x reference)
//
#include <hip/hip_runtime.h>

// HBMA fused: full-search block matching (16x16 blocks, +/-4 search) + predicted
// frame gather. N=8, C=3, H=W=1024.
//
// R5: software-pipelined strips (T3/T4 pattern). One 192-thread wg handles 4
// vertically adjacent 64x16 strips. Ref strips double-buffered in LDS, staged
// with global_load_lds dwordx4 (21 x 1KB chunks, 7 per wave); target rows
// double-buffered in registers (Ta/Tb, named arrays -> static indexing).
// Per strip: issue next strip's T loads (48) + stage chunks (7), then
// s_waitcnt vmcnt(55) keeps exactly those 55 newest ops in flight while
// guaranteeing current strip's data has landed; raw s_barrier (NOT
// __syncthreads -- that drains vmcnt(0) and kills the pipeline). SAD math,
// reduction, argmin tie-break identical to R4 (absmax was 0).
// OOB staging lanes load from a 16B zero block (MV region of d_out, zeroed by
// the init kernel every launch) -> LDS gets exact zero padding.

namespace {
constexpr int BLKi  = 16;
constexpr int NSDi  = 4;
constexpr int ND    = 9;
constexpr int NDISP = 81;
constexpr int Nn    = 8;
constexpr int Cc    = 3;
constexpr int Hh    = 1024;
constexpr int Ww    = 1024;
constexpr int BHn   = 64;
constexpr int STRIPW = 64;
constexpr int REFW  = 72;
constexpr int REFH  = 24;
constexpr int REF_FLOATS = Cc * REFH * REFW;   // 5184
constexpr int BUF_FLOATS = 5376;               // padded to 21*256
constexpr int CHUNKS     = 21;                 // 21 x 1024B per buffer
constexpr int CHUNKS_PW  = 7;                  // per wave
constexpr int MV_SIZE = Nn * 2 * BHn * BHn;    // 65536
constexpr int WGSIZE  = 192;
constexpr int DXW     = 3;
constexpr int BLKS_PER_WG = 4;
constexpr int SPW     = 4;                     // strips per wg (vertical)
constexpr int NWG     = Nn * (BHn / SPW) * (Ww / STRIPW);  // 2048
}

typedef const __attribute__((address_space(1))) void* gas_ptr;
typedef __attribute__((address_space(3))) void*       las_ptr;

__global__ void init_kernel(float* __restrict__ out) {
    int i = blockIdx.x * 256 + threadIdx.x;
    if (i < MV_SIZE) out[i] = 0.0f;   // MV output = zeros; also our zero-source
}

__device__ __forceinline__ void loadT(float (&T)[Cc][BLKi], const float* tgtn,
                                      int Y0, int X0, int lane) {
    #pragma unroll
    for (int c = 0; c < Cc; ++c)
        #pragma unroll
        for (int y = 0; y < BLKi; ++y)
            T[c][y] = tgtn[((size_t)c * Hh + (Y0 + y)) * Ww + X0 + lane];
}

__device__ __forceinline__ void stage(float* ldsbuf, const float* refn,
                                      const float* zsrc, int Y0, int X0,
                                      int wid, int lane) {
    #pragma unroll
    for (int k = 0; k < CHUNKS_PW; ++k) {
        const int ck  = wid * CHUNKS_PW + k;
        const int fi  = ck * 256 + lane * 4;       // float index in buffer
        const int c   = fi / (REFH * REFW);
        const int rm  = fi - c * (REFH * REFW);
        const int r   = rm / REFW;
        const int col = rm - r * REFW;
        const int gy  = Y0 - NSDi + r;
        const int gx  = X0 - NSDi + col;           // 16B chunk: cols col..col+3, one row
        const bool valid = (fi < REF_FLOATS) &&
                           ((unsigned)gy < (unsigned)Hh) &&
                           ((unsigned)gx < (unsigned)Ww);
        const float* src = valid ? (refn + ((size_t)c * Hh + gy) * Ww + gx) : zsrc;
        __builtin_amdgcn_global_load_lds((gas_ptr)src, (las_ptr)(ldsbuf + ck * 256),
                                         16, 0, 0);
    }
}

__device__ __forceinline__ void strip_body(
        const float* refn, const float* tgtn, float* predn, const float* zsrc,
        float* ldsR, float (*costL)[NDISP], int* bestL,
        float (&T)[Cc][BLKi], float (&Tn)[Cc][BLKi],
        int bufcur, int Y0, int X0, bool pre, int wid, int lane, int tid) {
    // ---- prefetch next strip, then wait for current strip's data ----
    if (pre) {
        loadT(Tn, tgtn, Y0 + BLKi, X0, lane);                       // 48 loads
        stage(ldsR + (bufcur ^ 1) * BUF_FLOATS, refn, zsrc,
              Y0 + BLKi, X0, wid, lane);                            // 7 chunks
        asm volatile("s_waitcnt vmcnt(55)" ::: "memory");           // keep 48+7
    } else {
        asm volatile("s_waitcnt vmcnt(0)" ::: "memory");
    }
    __builtin_amdgcn_s_barrier();
    asm volatile("" ::: "memory");

    const float* __restrict__ bp = ldsR + bufcur * BUF_FLOATS;
    const int d0 = wid * DXW;

    float acc[ND][DXW];
    #pragma unroll
    for (int jj = 0; jj < ND; ++jj)
        #pragma unroll
        for (int dd = 0; dd < DXW; ++dd) acc[jj][dd] = 0.0f;

    #pragma unroll
    for (int c = 0; c < Cc; ++c) {
        #pragma unroll
        for (int r = 0; r < REFH; ++r) {
            float rv[DXW];
            #pragma unroll
            for (int dd = 0; dd < DXW; ++dd)
                rv[dd] = bp[(c * REFH + r) * REFW + lane + d0 + dd];
            #pragma unroll
            for (int jj = 0; jj < ND; ++jj) {
                const int y = r - jj;                 // compile-time after unroll
                if (y >= 0 && y < BLKi) {
                    const float tv = T[c][y];
                    #pragma unroll
                    for (int dd = 0; dd < DXW; ++dd)
                        acc[jj][dd] += fabsf(rv[dd] - tv);
                }
            }
        }
    }

    // ---- reduce across the 16 lanes of each block group ----
    #pragma unroll
    for (int m = 1; m <= 8; m <<= 1)
        #pragma unroll
        for (int jj = 0; jj < ND; ++jj)
            #pragma unroll
            for (int dd = 0; dd < DXW; ++dd)
                acc[jj][dd] += __shfl_xor(acc[jj][dd], m, 64);

    // ---- publish costs ----
    const int bi  = lane >> 4;
    const int sub = lane & 15;
    #pragma unroll
    for (int jj = 0; jj < ND; ++jj) {
        if (sub == jj) {
            #pragma unroll
            for (int dd = 0; dd < DXW; ++dd)
                costL[bi][jj * ND + d0 + dd] = acc[jj][dd];
        }
    }
    asm volatile("s_waitcnt lgkmcnt(0)" ::: "memory");
    __builtin_amdgcn_s_barrier();
    asm volatile("" ::: "memory");

    // ---- argmin (wave 0): ascending index, strict <, matches jax scan ----
    if (wid == 0) {
        float bc = 3.4e38f;
        int   bj = NDISP;
        #pragma unroll
        for (int k = 0; k < 6; ++k) {
            int j = sub + (k << 4);
            if (j < NDISP) {
                float cst = costL[bi][j];
                if (cst < bc) { bc = cst; bj = j; }
            }
        }
        #pragma unroll
        for (int m = 1; m <= 8; m <<= 1) {
            float oc = __shfl_xor(bc, m, 64);
            int   oi = __shfl_xor(bj, m, 64);
            if (oc < bc || (oc == bc && oi < bj)) { bc = oc; bj = oi; }
        }
        if (sub == 0) bestL[bi] = bj;
    }
    asm volatile("s_waitcnt lgkmcnt(0)" ::: "memory");
    __builtin_amdgcn_s_barrier();
    asm volatile("" ::: "memory");

    // ---- gather predicted frame from LDS strip (zero padded) ----
    const int x  = tid & 63;
    const int gb = x >> 4;
    const int yy = tid >> 6;
    const int bb = bestL[gb];
    const int by = bb / ND;
    const int bx = bb % ND;
    #pragma unroll
    for (int c = 0; c < Cc; ++c) {
        for (int y = yy; y < BLKi; y += 3) {
            float v = bp[(c * REFH + (y + by)) * REFW + (x + bx)];
            predn[((size_t)c * Hh + (Y0 + y)) * Ww + X0 + x] = v;
        }
    }
    asm volatile("s_waitcnt lgkmcnt(0)" ::: "memory");   // LDS reads done -> buf free
    __builtin_amdgcn_s_barrier();
    asm volatile("" ::: "memory");
}

__global__ __launch_bounds__(WGSIZE) void hbma_kernel(
        const float* __restrict__ ref,
        const float* __restrict__ tgt,
        float* __restrict__ pred,
        const float* __restrict__ zsrc) {
    __shared__ float ldsR[2 * BUF_FLOATS];
    __shared__ float costL[BLKS_PER_WG][NDISP];
    __shared__ int   bestL[BLKS_PER_WG];

    const int tid  = (int)threadIdx.x;
    const int wid  = tid >> 6;
    const int lane = tid & 63;
    const int w    = (int)blockIdx.x;              // 0..2047
    const int n    = w >> 8;                       // 256 wg per image
    const int rem  = w & 255;
    const int ygrp = rem >> 4;                     // 0..15
    const int sx   = rem & 15;
    const int X0   = sx * STRIPW;
    const int Y0b  = ygrp * (SPW * BLKi);          // 4 strips: Y0b + i*16
    const float* refn  = ref  + (size_t)n * Cc * Hh * Ww;
    const float* tgtn  = tgt  + (size_t)n * Cc * Hh * Ww;
    float*       predn = pred + (size_t)n * Cc * Hh * Ww;

    float Ta[Cc][BLKi], Tb[Cc][BLKi];
    loadT(Ta, tgtn, Y0b, X0, lane);                // prologue: strip 0
    stage(ldsR, refn, zsrc, Y0b, X0, wid, lane);

    #pragma unroll 1
    for (int ii = 0; ii < SPW; ii += 2) {
        strip_body(refn, tgtn, predn, zsrc, ldsR, costL, bestL, Ta, Tb,
                   0, Y0b + ii * BLKi, X0, (ii + 1) < SPW, wid, lane, tid);
        strip_body(refn, tgtn, predn, zsrc, ldsR, costL, bestL, Tb, Ta,
                   1, Y0b + (ii + 1) * BLKi, X0, (ii + 2) < SPW, wid, lane, tid);
    }
}

extern "C" void kernel_launch(void* const* d_in, const int* in_sizes, int n_in,
                              void* d_out, int out_size, void* d_ws, size_t ws_size,
                              hipStream_t stream) {
    const float* ref = (const float*)d_in[0];
    const float* tgt = (const float*)d_in[1];
    float* out = (float*)d_out;

    init_kernel<<<dim3((MV_SIZE + 255) / 256), dim3(256), 0, stream>>>(out);

    // zsrc = MV region (guaranteed zero after init_kernel, never written after)
    hbma_kernel<<<dim3(NWG), dim3(WGSIZE), 0, stream>>>(ref, tgt, out + MV_SIZE, out);
}

// Round 6
// 383.912 us; speedup vs baseline: 1.6294x; 1.6294x over previous
//
#include <hip/hip_runtime.h>

// HBMA fused: full-search block matching (16x16 blocks, +/-4 search) + predicted
// frame gather. N=8, C=3, H=W=1024.
//
// R6: one independent 64-lane wave per 16x16 block; ZERO barriers.
// Lane = (col 0..15) x (dx-group 0..3); groups 0..2 own dx-index triplets
// {3g,3g+1,3g+2}, acc[9 dy][3 dx] = 27 live regs (group 3 idle in SAD).
// Ref tile (3ch x 24 x 24, zero-padded) staged by 7x global_load_lds width-16;
// 4-float chunks are aligned and never straddle an image row (X0,colc multiples
// of 16/4), so each chunk is fully-in or fully-out; fully-out chunks read a
// zeroed 16B block (MV region of d_out, zeroed by init_kernel each launch).
// Single wave -> s_waitcnt vmcnt/lgkmcnt instead of __syncthreads.
// Channel loop NOT unrolled (keeps body ~11KB, I-cache safe); r/dy/dx loops
// fully unrolled so acc/T are statically indexed (no scratch).
// Argmin: 64-lane parallel scan of 81 costs, lowest-index-wins tie-break
// (matches jax scan's strict <). Gather served from the LDS tile.

namespace {
constexpr int BLKi  = 16;
constexpr int NSDi  = 4;
constexpr int ND    = 9;
constexpr int NDISP = 81;
constexpr int Nn    = 8;
constexpr int Cc    = 3;
constexpr int Hh    = 1024;
constexpr int Ww    = 1024;
constexpr int BHn   = 64;
constexpr int BWn   = 64;
constexpr int RW    = 24;                  // tile width  (16 + 2*4)
constexpr int RH    = 24;                  // tile height
constexpr int REF_FLOATS = Cc * RH * RW;   // 1728
constexpr int CHUNKS     = REF_FLOATS / 4; // 432 16B chunks
constexpr int LDSF       = 448 * 4;        // 1792 floats (7 instr * 64 lanes * 4)
constexpr int MV_SIZE = Nn * 2 * BHn * BWn; // 65536
constexpr int NWG     = Nn * BHn * BWn;    // 32768
}

typedef const __attribute__((address_space(1))) void* gas_ptr;
typedef __attribute__((address_space(3))) void*       las_ptr;

__global__ void init_kernel(float* __restrict__ out) {
    int i = blockIdx.x * 256 + threadIdx.x;
    if (i < MV_SIZE) out[i] = 0.0f;   // MV output = zeros; doubles as zero-source
}

__global__ __launch_bounds__(64) void hbma_kernel(
        const float* __restrict__ ref,
        const float* __restrict__ tgt,
        float* __restrict__ pred,
        const float* __restrict__ zsrc) {
    __shared__ float ldsR[LDSF];
    __shared__ float costL[NDISP];

    const int lane = (int)threadIdx.x;
    const int w    = (int)blockIdx.x;            // 0..32767
    const int n    = w >> 12;
    const int rem  = w & 4095;
    const int Y0   = (rem >> 6) * BLKi;
    const int X0   = (rem & 63) * BLKi;
    const float* refn  = ref  + (size_t)n * Cc * Hh * Ww;
    const float* tgtn  = tgt  + (size_t)n * Cc * Hh * Ww;
    float*       predn = pred + (size_t)n * Cc * Hh * Ww;

    // ---- stage zero-padded ref tile [c][r(24)][col(24)] via global_load_lds ----
    #pragma unroll
    for (int k = 0; k < 7; ++k) {
        const int ck   = k * 64 + lane;          // chunk id (4 floats)
        const int c    = ck / (RH * RW / 4);     // /144
        const int rm   = ck - c * (RH * RW / 4);
        const int r    = rm / (RW / 4);          // /6
        const int colc = (rm - r * (RW / 4)) * 4;
        const int gy   = Y0 - NSDi + r;
        const int gx   = X0 - NSDi + colc;       // multiple of 4: chunk never straddles a row
        const bool valid = (ck < CHUNKS) &&
                           ((unsigned)gy < (unsigned)Hh) &&
                           ((unsigned)gx < (unsigned)Ww);
        const float* src = valid ? (refn + ((size_t)c * Hh + gy) * Ww + gx) : zsrc;
        __builtin_amdgcn_global_load_lds((gas_ptr)src, (las_ptr)(ldsR + k * 256),
                                         16, 0, 0);
    }
    asm volatile("s_waitcnt vmcnt(0)" ::: "memory");

    // ---- SAD: group g (lane>>4) handles dx indices 3g..3g+2 (g==3 idle) ----
    const int col = lane & 15;
    const int g   = lane >> 4;
    const int d0  = g * 3;                       // 0,3,6 (9 for idle group: harmless reads)

    float acc[ND][3];
    #pragma unroll
    for (int j = 0; j < ND; ++j) {
        acc[j][0] = 0.0f; acc[j][1] = 0.0f; acc[j][2] = 0.0f;
    }

    #pragma unroll 1
    for (int c = 0; c < Cc; ++c) {
        float T[BLKi];
        #pragma unroll
        for (int y = 0; y < BLKi; ++y)
            T[y] = tgtn[((size_t)c * Hh + (Y0 + y)) * Ww + X0 + col];

        #pragma unroll
        for (int r = 0; r < RH; ++r) {
            const float* rowp = ldsR + (c * RH + r) * RW + col + d0;
            const float rv0 = rowp[0], rv1 = rowp[1], rv2 = rowp[2];
            #pragma unroll
            for (int j = 0; j < ND; ++j) {
                const int y = r - j;             // compile-time after unroll
                if (y >= 0 && y < BLKi) {
                    const float tv = T[y];
                    acc[j][0] += fabsf(rv0 - tv);
                    acc[j][1] += fabsf(rv1 - tv);
                    acc[j][2] += fabsf(rv2 - tv);
                }
            }
        }
    }

    // ---- reduce over the 16 columns (lanes within each group) ----
    #pragma unroll
    for (int m = 1; m <= 8; m <<= 1)
        #pragma unroll
        for (int j = 0; j < ND; ++j) {
            acc[j][0] += __shfl_xor(acc[j][0], m, 64);
            acc[j][1] += __shfl_xor(acc[j][1], m, 64);
            acc[j][2] += __shfl_xor(acc[j][2], m, 64);
        }

    // ---- publish: lane (g,col==j) writes cost[j*9 + 3g + dd] ----
    if (g < 3 && col < ND) {
        const int j = col;
        costL[j * ND + d0 + 0] = acc[j][0];
        costL[j * ND + d0 + 1] = acc[j][1];
        costL[j * ND + d0 + 2] = acc[j][2];
    }
    asm volatile("s_waitcnt lgkmcnt(0)" ::: "memory");

    // ---- 64-lane argmin over 81, ascending index wins ties (jax strict <) ----
    float bc = costL[lane];
    int   bj = lane;
    if (lane < NDISP - 64) {
        float c2 = costL[lane + 64];
        if (c2 < bc) { bc = c2; bj = lane + 64; }
    }
    #pragma unroll
    for (int m = 1; m <= 32; m <<= 1) {
        float oc = __shfl_xor(bc, m, 64);
        int   oi = __shfl_xor(bj, m, 64);
        if (oc < bc || (oc == bc && oi < bj)) { bc = oc; bj = oi; }
    }
    const int by = bj / ND;                      // dy + 4
    const int bx = bj % ND;                      // dx + 4

    // ---- gather predicted block from LDS tile (already zero-padded) ----
    #pragma unroll 1
    for (int c = 0; c < Cc; ++c) {
        #pragma unroll
        for (int yy = 0; yy < 4; ++yy) {
            const int y = g * 4 + yy;
            const float v = ldsR[(c * RH + y + by) * RW + col + bx];
            predn[((size_t)c * Hh + (Y0 + y)) * Ww + X0 + col] = v;
        }
    }
}

extern "C" void kernel_launch(void* const* d_in, const int* in_sizes, int n_in,
                              void* d_out, int out_size, void* d_ws, size_t ws_size,
                              hipStream_t stream) {
    const float* ref = (const float*)d_in[0];
    const float* tgt = (const float*)d_in[1];
    float* out = (float*)d_out;

    init_kernel<<<dim3((MV_SIZE + 255) / 256), dim3(256), 0, stream>>>(out);

    // zsrc = MV region (zeroed by init_kernel on this stream, never written after)
    hbma_kernel<<<dim3(NWG), dim3(64), 0, stream>>>(ref, tgt, out + MV_SIZE, out);
}